// Round 1
// baseline (228.800 us; speedup 1.0000x reference)
//
#include <hip/hip_runtime.h>
#include <stdint.h>

typedef float  f32x4 __attribute__((ext_vector_type(4)));
typedef _Float16 f16x8 __attribute__((ext_vector_type(8)));
typedef _Float16 f16x4 __attribute__((ext_vector_type(4)));

#define BSZ  32768
#define MHOP 8
#define DDIM 128
#define HDIM 512
#define KDIM 256   // 2*DDIM
#define BT   8     // batches per block
#define ROWS 64    // BT*MHOP

// ---- prep: W1 fp32 [512][256] -> f16 [512][256] in d_ws ----
__global__ void prep_w1_f16(const float* __restrict__ W1, _Float16* __restrict__ W1h) {
    int i = (blockIdx.x * blockDim.x + threadIdx.x) * 4;
    float4 v = *reinterpret_cast<const float4*>(W1 + i);
    f16x4 o;
    o[0] = (_Float16)v.x; o[1] = (_Float16)v.y;
    o[2] = (_Float16)v.z; o[3] = (_Float16)v.w;
    *reinterpret_cast<f16x4*>(W1h + i) = o;
}

// ---- fused: GEMM(64x512,K=256) + relu + W2 dot + softmax(8) + V weighting ----
__global__ void __launch_bounds__(512) atten_mlp_kernel(
    const float* __restrict__ q_vec,
    const float* __restrict__ k_vec,
    const float* __restrict__ v_vec,
    const _Float16* __restrict__ W1h,
    const float* __restrict__ W2,
    float* __restrict__ out)
{
    __shared__ __align__(16) _Float16 a_q[BT * DDIM];    // 8x128, linear
    __shared__ __align__(16) _Float16 a_k[ROWS * DDIM];  // 64x128, chunk-XOR swizzled
    __shared__ float scores_part[8][ROWS];
    __shared__ float attn_lds[ROWS];

    const int t  = threadIdx.x;
    const int w  = t >> 6;    // wave 0..7 -> hidden cols [64w, 64w+64)
    const int l  = t & 63;
    const int lg = l >> 4;    // k-group within fragment
    const int ll = l & 15;    // row/col within fragment
    const long b0 = (long)blockIdx.x * BT;

    // ---- stage q tile (8 rows x 128 k), fp32 -> f16 ----
    if (t < 128) {
        int row = t >> 4, c = t & 15;
        const float4* s = reinterpret_cast<const float4*>(q_vec + (b0 + row) * DDIM + c * 8);
        float4 x0 = s[0], x1 = s[1];
        f16x8 p;
        p[0]=(_Float16)x0.x; p[1]=(_Float16)x0.y; p[2]=(_Float16)x0.z; p[3]=(_Float16)x0.w;
        p[4]=(_Float16)x1.x; p[5]=(_Float16)x1.y; p[6]=(_Float16)x1.z; p[7]=(_Float16)x1.w;
        *reinterpret_cast<f16x8*>(&a_q[row * DDIM + c * 8]) = p;
    }
    // ---- stage k tile (64 rows x 128 k), swizzle chunk ^= row&7 ----
    #pragma unroll
    for (int cc = 0; cc < 2; ++cc) {
        int cid = t + cc * 512;              // 1024 chunks of 8 elems
        int row = cid >> 4, c = cid & 15;
        const float4* s = reinterpret_cast<const float4*>(
            k_vec + b0 * (MHOP * DDIM) + row * DDIM + c * 8);
        float4 x0 = s[0], x1 = s[1];
        f16x8 p;
        p[0]=(_Float16)x0.x; p[1]=(_Float16)x0.y; p[2]=(_Float16)x0.z; p[3]=(_Float16)x0.w;
        p[4]=(_Float16)x1.x; p[5]=(_Float16)x1.y; p[6]=(_Float16)x1.z; p[7]=(_Float16)x1.w;
        int csw = c ^ (row & 7);
        *reinterpret_cast<f16x8*>(&a_k[row * DDIM + csw * 8]) = p;
    }
    __syncthreads();

    // ---- MFMA: rows 64 x cols 64(per wave), K=256 ----
    f32x4 acc[4][4] = {};
    const _Float16* w1base = W1h + (size_t)(w * 64 + ll) * KDIM;

    #pragma unroll
    for (int kf = 0; kf < 8; ++kf) {
        const int kk = kf * 32 + lg * 8;     // global k within [0,256)
        f16x8 bfrag[4];
        #pragma unroll
        for (int fc = 0; fc < 4; ++fc)
            bfrag[fc] = *reinterpret_cast<const f16x8*>(w1base + (size_t)(fc * 16) * KDIM + kk);
        #pragma unroll
        for (int fr = 0; fr < 4; ++fr) {
            f16x8 afrag;
            if (kf < 4) {
                // q-half: k in [0,128): A row (b,m) -> q[b], b = row>>3
                int b = fr * 2 + (ll >> 3);
                afrag = *reinterpret_cast<const f16x8*>(&a_q[b * DDIM + kk]);
            } else {
                // k-half: k in [128,256) -> a_k at kk-128, swizzled
                int row = fr * 16 + ll;
                int chunk = (kf - 4) * 4 + lg;
                afrag = *reinterpret_cast<const f16x8*>(&a_k[row * DDIM + ((chunk ^ (row & 7)) * 8)]);
            }
            #pragma unroll
            for (int fc = 0; fc < 4; ++fc)
                acc[fr][fc] = __builtin_amdgcn_mfma_f32_16x16x32_f16(afrag, bfrag[fc], acc[fr][fc], 0, 0, 0);
        }
    }

    // ---- epilogue: scores[row] = sum_h W2[h]*relu(h_pre) (partial over this wave's 64 cols) ----
    float w2r[4];
    #pragma unroll
    for (int fc = 0; fc < 4; ++fc) w2r[fc] = W2[w * 64 + fc * 16 + ll];

    #pragma unroll
    for (int fr = 0; fr < 4; ++fr) {
        #pragma unroll
        for (int j = 0; j < 4; ++j) {
            float s = 0.f;
            #pragma unroll
            for (int fc = 0; fc < 4; ++fc)
                s += w2r[fc] * fmaxf(acc[fr][fc][j], 0.f);
            // reduce over the 16 lanes (ll) sharing this row set
            s += __shfl_xor(s, 1);
            s += __shfl_xor(s, 2);
            s += __shfl_xor(s, 4);
            s += __shfl_xor(s, 8);
            if (ll == 0) scores_part[w][fr * 16 + lg * 4 + j] = s;
        }
    }
    __syncthreads();

    // ---- cross-wave reduce + softmax over m (groups of 8) ----
    if (t < ROWS) {
        float s = 0.f;
        #pragma unroll
        for (int ww = 0; ww < 8; ++ww) s += scores_part[ww][t];
        float mx = s;
        mx = fmaxf(mx, __shfl_xor(mx, 1, 8));
        mx = fmaxf(mx, __shfl_xor(mx, 2, 8));
        mx = fmaxf(mx, __shfl_xor(mx, 4, 8));
        float e = __expf(s - mx);
        float sum = e;
        sum += __shfl_xor(sum, 1, 8);
        sum += __shfl_xor(sum, 2, 8);
        sum += __shfl_xor(sum, 4, 8);
        attn_lds[t] = e / sum;
    }
    __syncthreads();

    // ---- output: out[b][d] = sum_m attn[b][m] * v[b][m][d]  (float2 per thread) ----
    {
        int b = t >> 6;
        int d = (t & 63) * 2;
        const float* vb = v_vec + (b0 + b) * (MHOP * DDIM) + d;
        float a0 = 0.f, a1 = 0.f;
        #pragma unroll
        for (int m = 0; m < MHOP; ++m) {
            float at = attn_lds[b * 8 + m];
            float2 vv = *reinterpret_cast<const float2*>(vb + m * DDIM);
            a0 += at * vv.x;
            a1 += at * vv.y;
        }
        float2 o; o.x = a0; o.y = a1;
        *reinterpret_cast<float2*>(out + (b0 + b) * DDIM + d) = o;
    }
}

extern "C" void kernel_launch(void* const* d_in, const int* in_sizes, int n_in,
                              void* d_out, int out_size, void* d_ws, size_t ws_size,
                              hipStream_t stream) {
    const float* q  = (const float*)d_in[0];
    const float* k  = (const float*)d_in[1];
    const float* v  = (const float*)d_in[2];
    const float* W1 = (const float*)d_in[3];
    const float* W2 = (const float*)d_in[4];
    _Float16* W1h = (_Float16*)d_ws;   // 512*256*2 = 256 KB

    prep_w1_f16<<<(HDIM * KDIM) / (256 * 4), 256, 0, stream>>>(W1, W1h);
    atten_mlp_kernel<<<BSZ / BT, 512, 0, stream>>>(q, k, v, W1h, W2, (float*)d_out);
}

// Round 2
// 182.574 us; speedup vs baseline: 1.2532x; 1.2532x over previous
//
#include <hip/hip_runtime.h>
#include <stdint.h>

typedef float    f32x4 __attribute__((ext_vector_type(4)));
typedef _Float16 f16x8 __attribute__((ext_vector_type(8)));
typedef _Float16 f16x4 __attribute__((ext_vector_type(4)));

#define BSZ  32768
#define MHOP 8
#define DDIM 128
#define HDIM 512
#define KDIM 256   // 2*DDIM
#define BT   8     // batches per tile
#define ROWS 64    // BT*MHOP
#define NT   8     // tiles per block
#define NBLK 512   // NBLK*NT*BT == BSZ

// ---- prep: W1 fp32 [512][256] -> f16 [512][256] in d_ws ----
__global__ void prep_w1_f16(const float* __restrict__ W1, _Float16* __restrict__ W1h) {
    int i = (blockIdx.x * blockDim.x + threadIdx.x) * 4;
    float4 v = *reinterpret_cast<const float4*>(W1 + i);
    f16x4 o;
    o[0] = (_Float16)v.x; o[1] = (_Float16)v.y;
    o[2] = (_Float16)v.z; o[3] = (_Float16)v.w;
    *reinterpret_cast<f16x4*>(W1h + i) = o;
}

__device__ __forceinline__ f16x8 cvt_f16x8(float4 x0, float4 x1) {
    f16x8 p;
    p[0]=(_Float16)x0.x; p[1]=(_Float16)x0.y; p[2]=(_Float16)x0.z; p[3]=(_Float16)x0.w;
    p[4]=(_Float16)x1.x; p[5]=(_Float16)x1.y; p[6]=(_Float16)x1.z; p[7]=(_Float16)x1.w;
    return p;
}

// ---- fused persistent kernel: per tile GEMM(64x512,K=256)+relu+W2+softmax(8)+V ----
__global__ void __launch_bounds__(512, 2) atten_mlp_kernel(
    const float* __restrict__ q_vec,
    const float* __restrict__ k_vec,
    const float* __restrict__ v_vec,
    const _Float16* __restrict__ W1h,
    const float* __restrict__ W2,
    float* __restrict__ out)
{
    __shared__ __align__(16) _Float16 a_q[2][BT * DDIM];    // 8x128 per buf
    __shared__ __align__(16) _Float16 a_k[2][ROWS * DDIM];  // 64x128, chunk-XOR swizzled
    __shared__ float scores_part[8][ROWS];
    __shared__ float attn_lds[ROWS];

    const int t  = threadIdx.x;
    const int w  = t >> 6;    // wave 0..7 -> hidden cols [64w, 64w+64)
    const int l  = t & 63;
    const int lg = l >> 4;    // k-group within fragment
    const int ll = l & 15;    // row/col within fragment

    // ---- W1 fragments: loaded ONCE per block into registers (128 VGPR) ----
    f16x8 w1f[8][4];  // [kf][fc]
    {
        const _Float16* w1base = W1h + (size_t)(w * 64 + ll) * KDIM + lg * 8;
        #pragma unroll
        for (int kf = 0; kf < 8; ++kf)
            #pragma unroll
            for (int fc = 0; fc < 4; ++fc)
                w1f[kf][fc] = *reinterpret_cast<const f16x8*>(
                    w1base + (size_t)(fc * 16) * KDIM + kf * 32);
    }
    float w2r[4];
    #pragma unroll
    for (int fc = 0; fc < 4; ++fc) w2r[fc] = W2[w * 64 + fc * 16 + ll];

    const long tile0 = (long)blockIdx.x * NT;

    // ---- prologue: stage tile 0 into buf 0 ----
    {
        const long b0p = tile0 * BT;
        #pragma unroll
        for (int cc = 0; cc < 2; ++cc) {
            int cid = t + cc * 512, row = cid >> 4, c = cid & 15;
            const float4* s = reinterpret_cast<const float4*>(
                k_vec + b0p * (MHOP * DDIM) + (size_t)cid * 8);
            float4 x0 = s[0], x1 = s[1];
            *reinterpret_cast<f16x8*>(&a_k[0][row * DDIM + (c ^ (row & 7)) * 8]) = cvt_f16x8(x0, x1);
        }
        if (t < 256) {
            float4 x = reinterpret_cast<const float4*>(q_vec + b0p * DDIM)[t];
            f16x4 p;
            p[0]=(_Float16)x.x; p[1]=(_Float16)x.y; p[2]=(_Float16)x.z; p[3]=(_Float16)x.w;
            *reinterpret_cast<f16x4*>(&a_q[0][t * 4]) = p;
        }
    }
    __syncthreads();

    int cur = 0;
    for (int it = 0; it < NT; ++it) {
        const long b0 = (tile0 + it) * BT;
        const bool have_next = (it + 1 < NT);

        // ---- 1. issue next tile's k/q global loads (regs, consumed after sync1) ----
        float4 kr0, kr1, kr2, kr3, qr;
        if (have_next) {
            const long bn = b0 + BT;
            const float4* ks = reinterpret_cast<const float4*>(k_vec + bn * (MHOP * DDIM));
            kr0 = ks[t * 2];           kr1 = ks[t * 2 + 1];
            kr2 = ks[(t + 512) * 2];   kr3 = ks[(t + 512) * 2 + 1];
            if (t < 256) qr = reinterpret_cast<const float4*>(q_vec + bn * DDIM)[t];
        }

        // ---- 2. MFMA: rows 64 x cols 64/wave, K=256; B from registers ----
        f32x4 acc[4][4] = {};
        const _Float16* aq = &a_q[cur][0];
        const _Float16* ak = &a_k[cur][0];
        #pragma unroll
        for (int kf = 0; kf < 8; ++kf) {
            const int kk = kf * 32 + lg * 8;
            #pragma unroll
            for (int fr = 0; fr < 4; ++fr) {
                f16x8 afrag;
                if (kf < 4) {
                    int b = fr * 2 + (ll >> 3);
                    afrag = *reinterpret_cast<const f16x8*>(&aq[b * DDIM + kk]);
                } else {
                    int row = fr * 16 + ll;
                    int chunk = (kf - 4) * 4 + lg;
                    afrag = *reinterpret_cast<const f16x8*>(&ak[row * DDIM + ((chunk ^ (row & 7)) * 8)]);
                }
                #pragma unroll
                for (int fc = 0; fc < 4; ++fc)
                    acc[fr][fc] = __builtin_amdgcn_mfma_f32_16x16x32_f16(afrag, w1f[kf][fc], acc[fr][fc], 0, 0, 0);
            }
        }

        // ---- 3. partial scores: sum_h W2[h]*relu(.) over this wave's 64 cols ----
        #pragma unroll
        for (int fr = 0; fr < 4; ++fr) {
            #pragma unroll
            for (int j = 0; j < 4; ++j) {
                float s = 0.f;
                #pragma unroll
                for (int fc = 0; fc < 4; ++fc)
                    s += w2r[fc] * fmaxf(acc[fr][fc][j], 0.f);
                s += __shfl_xor(s, 1);
                s += __shfl_xor(s, 2);
                s += __shfl_xor(s, 4);
                s += __shfl_xor(s, 8);
                if (ll == 0) scores_part[w][fr * 16 + lg * 4 + j] = s;
            }
        }
        __syncthreads();   // sync1

        // ---- 4. issue v loads for THIS tile (used after sync2) ----
        float2 vr[8];
        {
            const float* vb = v_vec + (b0 + (t >> 6)) * (MHOP * DDIM) + (t & 63) * 2;
            #pragma unroll
            for (int m = 0; m < MHOP; ++m)
                vr[m] = *reinterpret_cast<const float2*>(vb + m * DDIM);
        }

        // ---- 5. write next tile into buf[cur^1] ----
        if (have_next) {
            #pragma unroll
            for (int cc = 0; cc < 2; ++cc) {
                int cid = t + cc * 512, row = cid >> 4, c = cid & 15;
                f16x8 p = (cc == 0) ? cvt_f16x8(kr0, kr1) : cvt_f16x8(kr2, kr3);
                *reinterpret_cast<f16x8*>(&a_k[cur ^ 1][row * DDIM + (c ^ (row & 7)) * 8]) = p;
            }
            if (t < 256) {
                f16x4 p;
                p[0]=(_Float16)qr.x; p[1]=(_Float16)qr.y; p[2]=(_Float16)qr.z; p[3]=(_Float16)qr.w;
                *reinterpret_cast<f16x4*>(&a_q[cur ^ 1][t * 4]) = p;
            }
        }

        // ---- 6. cross-wave reduce + softmax over the 8 hops ----
        if (t < ROWS) {
            float s = 0.f;
            #pragma unroll
            for (int ww = 0; ww < 8; ++ww) s += scores_part[ww][t];
            float mx = s;
            mx = fmaxf(mx, __shfl_xor(mx, 1, 8));
            mx = fmaxf(mx, __shfl_xor(mx, 2, 8));
            mx = fmaxf(mx, __shfl_xor(mx, 4, 8));
            float e = __expf(s - mx);
            float sum = e;
            sum += __shfl_xor(sum, 1, 8);
            sum += __shfl_xor(sum, 2, 8);
            sum += __shfl_xor(sum, 4, 8);
            attn_lds[t] = e / sum;
        }
        __syncthreads();   // sync2 (also guards buf[cur^1] writes)

        // ---- 7. output: out[b][d] = sum_m attn * v ----
        {
            int b = t >> 6, d = (t & 63) * 2;
            float a0 = 0.f, a1 = 0.f;
            #pragma unroll
            for (int m = 0; m < MHOP; ++m) {
                float at = attn_lds[b * 8 + m];
                a0 += at * vr[m].x;
                a1 += at * vr[m].y;
            }
            float2 o; o.x = a0; o.y = a1;
            *reinterpret_cast<float2*>(out + (b0 + b) * DDIM + d) = o;
        }

        cur ^= 1;
    }
}

extern "C" void kernel_launch(void* const* d_in, const int* in_sizes, int n_in,
                              void* d_out, int out_size, void* d_ws, size_t ws_size,
                              hipStream_t stream) {
    const float* q  = (const float*)d_in[0];
    const float* k  = (const float*)d_in[1];
    const float* v  = (const float*)d_in[2];
    const float* W1 = (const float*)d_in[3];
    const float* W2 = (const float*)d_in[4];
    _Float16* W1h = (_Float16*)d_ws;   // 512*256*2 = 256 KB

    prep_w1_f16<<<(HDIM * KDIM) / (256 * 4), 256, 0, stream>>>(W1, W1h);
    atten_mlp_kernel<<<NBLK, 512, 0, stream>>>(q, k, v, W1h, W2, (float*)d_out);
}